// Round 3
// baseline (149.210 us; speedup 1.0000x reference)
//
#include <hip/hip_runtime.h>

// LogicGatedSNN fused kernel for MI355X (gfx950) — round 3 (round-2 compile fix).
//
// Round 1 post-mortem: block-per-row + 2x __syncthreads around an LDS reduce
// serialized phase 1 (syn read / dot) against phase 2 (trace RMW); HBM BW
// stalled at 36% of peak (2.9 TB/s) with VALUBusy 7%. 538 MB of unavoidable
// HBM traffic per dispatch -> 85 us floor; we ran 186 us.
//
// This version: ONE WAVE PER ROW. 256-thread block = 4 fully independent
// rows. Butterfly __shfl_xor reduce leaves the row-sum in every lane:
// no LDS, no barriers, every wave streams continuously. Nontemporal trace
// stores keep the L3 read-resident set (which absorbs ~268 MB/replay) clean.
// Round-2 fix: __builtin_nontemporal_store needs a native clang vector type,
// not HIP's float4 struct -> use ext_vector_type(4) throughout phase I/O.
//
// Exactness: x in {0,1}, w in {0,1} -> phase-1 sum is a sum of exact small
// integers (<= 8192 < 2^24), bit-exact under any order. Scalar update path
// uses __fmul_rn/__fadd_rn to pin rounding at the spike comparison boundary.
//
// Output layout (float32, flat): [spikes O][new_mem O][new_thr O][new_trace O*I]

constexpr int O_FEAT = 8192;
constexpr int I_FEAT = 8192;
constexpr float STATE_THR = 50.0f;

typedef float f32x4 __attribute__((ext_vector_type(4)));

__global__ __launch_bounds__(256) void snn_fused_wave(
    const float* __restrict__ x,    // [I] spike_input (0/1)
    const float* __restrict__ syn,  // [O*I] synapse_states
    const float* __restrict__ mp,   // [O] membrane_potential
    const float* __restrict__ thr,  // [O] adaptive_threshold
    const float* __restrict__ tr,   // [O*I] eligibility_trace
    float* __restrict__ out)        // [3*O + O*I]
{
    const int lane = threadIdx.x & 63;
    const int o = (blockIdx.x * blockDim.x + threadIdx.x) >> 6;  // row = global wave id
    const long long rowoff = (long long)o * I_FEAT;

    const f32x4* __restrict__ x4 = (const f32x4*)x;
    const f32x4* __restrict__ s4 = (const f32x4*)(syn + rowoff);
    const f32x4* __restrict__ t4 = (const f32x4*)(tr + rowoff);
    f32x4* __restrict__ n4 = (f32x4*)(out + 3LL * O_FEAT + rowoff);

    // Phase 1: dot((syn>50), x). 2048 float4 per row, 32 per lane.
    float sum = 0.0f;
#pragma unroll 4
    for (int j = 0; j < 32; ++j) {
        const int idx = j * 64 + lane;
        const f32x4 sv = s4[idx];
        const f32x4 xv = x4[idx];  // L1/L2-resident (32 KiB, shared by all rows)
        sum += (sv.x > STATE_THR) ? xv.x : 0.0f;
        sum += (sv.y > STATE_THR) ? xv.y : 0.0f;
        sum += (sv.z > STATE_THR) ? xv.z : 0.0f;
        sum += (sv.w > STATE_THR) ? xv.w : 0.0f;
    }

    // Butterfly reduce: every lane ends with the full row sum. No LDS.
#pragma unroll
    for (int off = 1; off < 64; off <<= 1)
        sum += __shfl_xor(sum, off, 64);

    // Scalar neuron update (all lanes compute identically; lane 0 stores).
    const float v_mem = __fadd_rn(__fmul_rn(mp[o], 0.9f), sum);
    const float th = thr[o];
    const float s = (v_mem >= th) ? 1.0f : 0.0f;
    if (lane == 0) {
        out[o] = s;
        out[O_FEAT + o] = __fmul_rn(__fmul_rn(v_mem, 1.0f - s), 0.1f);
        float nth = __fadd_rn(th, __fmul_rn(s - 0.1f, 0.1f));
        out[2 * O_FEAT + o] = fminf(fmaxf(nth, 1.0f), 20.0f);
    }

    // Phase 2: new_trace = clip(tr*0.8 + s*x, 0, 5). Streaming RMW.
#pragma unroll 4
    for (int j = 0; j < 32; ++j) {
        const int idx = j * 64 + lane;
        const f32x4 tv = t4[idx];
        const f32x4 xv = x4[idx];
        f32x4 r;
        r.x = fminf(fmaxf(__fadd_rn(__fmul_rn(tv.x, 0.8f), s * xv.x), 0.0f), 5.0f);
        r.y = fminf(fmaxf(__fadd_rn(__fmul_rn(tv.y, 0.8f), s * xv.y), 0.0f), 5.0f);
        r.z = fminf(fmaxf(__fadd_rn(__fmul_rn(tv.z, 0.8f), s * xv.z), 0.0f), 5.0f);
        r.w = fminf(fmaxf(__fadd_rn(__fmul_rn(tv.w, 0.8f), s * xv.w), 0.0f), 5.0f);
        __builtin_nontemporal_store(r, &n4[idx]);  // streaming write, never re-read
    }
}

extern "C" void kernel_launch(void* const* d_in, const int* in_sizes, int n_in,
                              void* d_out, int out_size, void* d_ws, size_t ws_size,
                              hipStream_t stream) {
    const float* x   = (const float*)d_in[0];  // spike_input [I]
    const float* syn = (const float*)d_in[1];  // synapse_states [O*I]
    const float* mp  = (const float*)d_in[2];  // membrane_potential [O]
    const float* th  = (const float*)d_in[3];  // adaptive_threshold [O]
    const float* tr  = (const float*)d_in[4];  // eligibility_trace [O*I]
    float* out = (float*)d_out;

    // 1 wave per row, 4 rows per 256-thread block -> 2048 blocks (8/CU).
    snn_fused_wave<<<O_FEAT / 4, 256, 0, stream>>>(x, syn, mp, th, tr, out);
}